// Round 7
// baseline (226.957 us; speedup 1.0000x reference)
//
#include <hip/hip_runtime.h>
#include <hip/hip_bf16.h>
#include <cstdint>
#include <cstddef>

// Problem constants
constexpr int B_ = 2, T_ = 4096, C_ = 768, H_ = 12, HD_ = 64;
constexpr int M_ = B_ * T_;      // 8192 rows of x
constexpr int NQKV_ = 3 * C_;    // 2304

typedef __bf16 bf16_t;
typedef __bf16 bf16x8 __attribute__((ext_vector_type(8)));
typedef __bf16 bf16x4 __attribute__((ext_vector_type(4)));
typedef __bf16 bf16x2 __attribute__((ext_vector_type(2)));
typedef float  f32x4  __attribute__((ext_vector_type(4)));
typedef float  f32x16 __attribute__((ext_vector_type(16)));
typedef unsigned int u32;
typedef unsigned int u32x4 __attribute__((ext_vector_type(4)));

typedef const __attribute__((address_space(1))) void* gas_t;
typedef __attribute__((address_space(3))) void* las_t;

// Q pre-scale: 1/sqrt(64) * log2(e)  (softmax done in exp2 domain)
#define QSCALE 0.1803368801111204f

static __device__ __forceinline__ u32 pkbf16(float a, float b) {
  bf16x2 t;
  t[0] = (bf16_t)a;
  t[1] = (bf16_t)b;
  return __builtin_bit_cast(u32, t);
}

// ---------------------------------------------------------------------------
// f32 -> bf16 conversion, vectorized by 4
// ---------------------------------------------------------------------------
__global__ void cvt_f32_bf16_v4(const float* __restrict__ s,
                                bf16_t* __restrict__ d, int n4) {
  int i = blockIdx.x * blockDim.x + threadIdx.x;
  const int st = gridDim.x * blockDim.x;
  for (; i < n4; i += st) {
    const float4 v = reinterpret_cast<const float4*>(s)[i];
    bf16x4 o;
    o[0] = (bf16_t)v.x; o[1] = (bf16_t)v.y;
    o[2] = (bf16_t)v.z; o[3] = (bf16_t)v.w;
    reinterpret_cast<bf16x4*>(d)[i] = o;
  }
}

// ===========================================================================
// Staged GEMM core (m97 structure): 128x128 tile, BK=32, dbuf LDS 32 KB,
// global_load_lds width=16, pre-swizzled source (chunk ^= row&3).
// ===========================================================================
#define GEMM_CORE(Xb, Wb)                                                     \
  __shared__ __align__(16) char lds[32768];                                   \
  const int tid = threadIdx.x, lane = tid & 63, wave = tid >> 6;              \
  const int r16 = lane & 15, g = lane >> 4;                                   \
  const int wr = wave >> 1, wc = wave & 1;                                    \
  const int m0 = blockIdx.y * 128;                                            \
  const int n0 = blockIdx.x * 128;                                            \
  int prow[2], goff[2];                                                       \
  _Pragma("unroll")                                                           \
  for (int i = 0; i < 2; ++i) {                                               \
    const int p = (wave * 2 + i) * 64 + lane;                                 \
    prow[i] = p >> 2;                                                         \
    goff[i] = ((p & 3) ^ (prow[i] & 3)) * 8;                                  \
  }                                                                           \
  auto stage = [&](int buf, int k0) {                                         \
    char* const base = lds + buf * 16384;                                     \
    _Pragma("unroll")                                                         \
    for (int i = 0; i < 2; ++i) {                                             \
      __builtin_amdgcn_global_load_lds(                                       \
          (gas_t)(Xb + (size_t)prow[i] * C_ + k0 + goff[i]),                  \
          (las_t)(base + (wave * 2 + i) * 1024), 16, 0, 0);                   \
      __builtin_amdgcn_global_load_lds(                                       \
          (gas_t)(Wb + (size_t)prow[i] * C_ + k0 + goff[i]),                  \
          (las_t)(base + 8192 + (wave * 2 + i) * 1024), 16, 0, 0);            \
    }                                                                         \
  };                                                                          \
  f32x4 acc[4][4] = {};                                                       \
  const int kswz = (g ^ (r16 & 3)) * 16;                                      \
  stage(0, 0);                                                                \
  __syncthreads();                                                            \
  constexpr int KT = C_ / 32;                                                 \
  for (int kt = 0; kt < KT; ++kt) {                                           \
    if (kt + 1 < KT) stage((kt + 1) & 1, (kt + 1) * 32);                      \
    const char* Ab = lds + (kt & 1) * 16384;                                  \
    const char* Bb = Ab + 8192;                                               \
    bf16x8 a[4], b[4];                                                        \
    _Pragma("unroll")                                                         \
    for (int i = 0; i < 4; ++i)                                               \
      a[i] = *reinterpret_cast<const bf16x8*>(                                \
          Ab + (wr * 64 + i * 16 + r16) * 64 + kswz);                         \
    _Pragma("unroll")                                                         \
    for (int j = 0; j < 4; ++j)                                               \
      b[j] = *reinterpret_cast<const bf16x8*>(                                \
          Bb + (wc * 64 + j * 16 + r16) * 64 + kswz);                         \
    _Pragma("unroll")                                                         \
    for (int i = 0; i < 4; ++i)                                               \
      _Pragma("unroll")                                                       \
      for (int j = 0; j < 4; ++j)                                             \
        acc[i][j] = __builtin_amdgcn_mfma_f32_16x16x32_bf16(                  \
            a[i], b[j], acc[i][j], 0, 0, 0);                                  \
    __syncthreads();                                                          \
  }

// ---------------------------------------------------------------------------
// QKV projection -> Q,K ([B,H,T,64]) and V transposed ([B,H,64,T]).
// ---------------------------------------------------------------------------
__global__ __launch_bounds__(256) void gemm_qkv(
    const bf16_t* __restrict__ X, const bf16_t* __restrict__ W,
    bf16_t* __restrict__ Q, bf16_t* __restrict__ K, bf16_t* __restrict__ Vt) {
  GEMM_CORE(X + (size_t)blockIdx.y * 128 * C_,
            W + (size_t)blockIdx.x * 128 * C_)

#pragma unroll
  for (int j = 0; j < 4; ++j) {
    const int col = n0 + wc * 64 + j * 16 + r16;
    const int which = col / C_;           // 0=Q, 1=K, 2=V
    const int c = col - which * C_;
    const int h = c >> 6, d = c & 63;
#pragma unroll
    for (int i = 0; i < 4; ++i) {
#pragma unroll
      for (int r = 0; r < 4; ++r) {
        const int row = m0 + wr * 64 + i * 16 + g * 4 + r;
        const int bb = row >> 12, t = row & (T_ - 1);
        const float v = acc[i][j][r];
        if (which == 0)
          Q[(((size_t)(bb * H_ + h)) * T_ + t) * HD_ + d] = (bf16_t)(v * QSCALE);
        else if (which == 1)
          K[(((size_t)(bb * H_ + h)) * T_ + t) * HD_ + d] = (bf16_t)v;
        else
          Vt[(((size_t)(bb * H_ + h)) * HD_ + d) * (size_t)T_ + t] = (bf16_t)v;
      }
    }
  }
}

// ---------------------------------------------------------------------------
// Output projection: A[8192][768] * Wp[768][768]^T -> f32 out
// ---------------------------------------------------------------------------
__global__ __launch_bounds__(256) void gemm_proj(
    const bf16_t* __restrict__ A, const bf16_t* __restrict__ W,
    float* __restrict__ Out) {
  GEMM_CORE(A + (size_t)blockIdx.y * 128 * C_,
            W + (size_t)blockIdx.x * 128 * C_)

#pragma unroll
  for (int j = 0; j < 4; ++j) {
    const int col = n0 + wc * 64 + j * 16 + r16;
#pragma unroll
    for (int i = 0; i < 4; ++i)
#pragma unroll
      for (int r = 0; r < 4; ++r) {
        const int row = m0 + wr * 64 + i * 16 + g * 4 + r;
        Out[(size_t)row * C_ + col] = acc[i][j][r];
      }
  }
}

// ---------------------------------------------------------------------------
// Causal flash attention v6: 32x32x16 MFMA, swapped QK^T, fixed-shift softmax,
// MFMA row-sum, in-register P->A (pack+permlane32_swap).
// NEW: 2-wave blocks; each wave owns 64 queries as TWO 32-row groups taken
// from PAIRED q-tiles (64j and 64(63-j)) -> uniform work per block AND each
// LDS kf/vf read feeds two q-groups (halved LDS amplification) AND the two
// groups give intra-wave MFMA||VALU ILP.
// Grid: (B*H = 24, 32 pairs).  K/V 64-key tiles dbuf in LDS, 32 KB.
// ---------------------------------------------------------------------------
__global__ __launch_bounds__(128, 2) void attn_fwd(
    const bf16_t* __restrict__ Q, const bf16_t* __restrict__ K,
    const bf16_t* __restrict__ Vt, bf16_t* __restrict__ O) {
  __shared__ __align__(16) char lds[32768];
  const int tid = threadIdx.x;
  const int lane = tid & 63, wave = tid >> 6;
  const int c32 = lane & 31, h = lane >> 5;
  const int bh = blockIdx.x;
  const int j = blockIdx.y;                 // pair index
  const int qA0 = 64 * j + 32 * wave;       // light group base (this wave)
  const int qB0 = 64 * (63 - j) + 32 * wave; // heavy group base (this wave)

  const bf16_t* Qb = Q + (size_t)bh * T_ * HD_;
  const bf16_t* Kb = K + (size_t)bh * T_ * HD_;
  const bf16_t* Vb = Vt + (size_t)bh * HD_ * T_;

  // Q fragments (B operand): col=query=c32, k = dg*16 + h*8 + j
  bf16x8 qfA[4], qfB[4];
#pragma unroll
  for (int dg = 0; dg < 4; ++dg) {
    qfA[dg] = *reinterpret_cast<const bf16x8*>(
        Qb + (size_t)(qA0 + c32) * HD_ + dg * 16 + h * 8);
    qfB[dg] = *reinterpret_cast<const bf16x8*>(
        Qb + (size_t)(qB0 + c32) * HD_ + dg * 16 + h * 8);
  }

  bf16x8 ones;
#pragma unroll
  for (int q = 0; q < 8; ++q) ones[q] = (bf16_t)1.0f;

  f32x16 o0A = {}, o1A = {}, lacA = {};
  f32x16 o0B = {}, o1B = {}, lacB = {};

  // staging: wave 0 stages the K tile, wave 1 the V tile (8 x 16B insts each;
  // per inst the 64 lanes cover 8 rows x 8 chunks, source chunk pre-swizzled
  // by row&7 so the linear LDS dest yields the swizzled layout).
  auto STAGE = [&](int t, int buf) {
    char* const base = lds + buf * 16384 + wave * 8192;
#pragma unroll
    for (int i = 0; i < 8; ++i) {
      const int r = i * 8 + (lane >> 3);
      const int c = (lane & 7) ^ (r & 7);
      const bf16_t* p = (wave == 0)
          ? Kb + (size_t)(t * 64 + r) * HD_ + c * 8
          : Vb + (size_t)r * T_ + t * 64 + c * 8;
      __builtin_amdgcn_global_load_lds((gas_t)p, (las_t)(base + i * 1024),
                                       16, 0, 0);
    }
  };

  const int nt = 64 - j;   // covers heavy tile's keys
  STAGE(0, 0);
  __syncthreads();

  for (int t = 0; t < nt; ++t) {
    if (t + 1 < nt) STAGE(t + 1, (t + 1) & 1);
    const char* kl = lds + (t & 1) * 16384;
    const char* vl = kl + 8192;
#pragma unroll
    for (int ks = 0; ks < 2; ++ks) {
      const int kb0 = t * 64 + ks * 32;
      if (kb0 < qB0 + 32) {          // B heavy: A-active implies B-active
        const bool actA = kb0 < qA0 + 32;
        // ---- K fragments (shared by both groups) ----
        bf16x8 kf[4];
#pragma unroll
        for (int dg = 0; dg < 4; ++dg)
          kf[dg] = *reinterpret_cast<const bf16x8*>(
              kl + (ks * 32 + c32) * 128 + (((dg * 2 + h) ^ (c32 & 7)) << 4));
        // ---- group B: S^T, mask, exp, pack ----
        f32x16 sB = {};
        __builtin_amdgcn_s_setprio(1);
#pragma unroll
        for (int dg = 0; dg < 4; ++dg)
          sB = __builtin_amdgcn_mfma_f32_32x32x16_bf16(kf[dg], qfB[dg], sB,
                                                       0, 0, 0);
        __builtin_amdgcn_s_setprio(0);
        if (kb0 + 31 > qB0) {
          const int qabs = qB0 + c32;
          const int kbh = kb0 + 4 * h;
#pragma unroll
          for (int r = 0; r < 16; ++r)
            if (kbh + (r & 3) + 8 * (r >> 2) > qabs) sB[r] = -130.f;
        }
#pragma unroll
        for (int r = 0; r < 16; ++r) sB[r] = exp2f(sB[r]);
        u32 Y0 = pkbf16(sB[0], sB[1]),  Y1 = pkbf16(sB[2], sB[3]);
        u32 Y2 = pkbf16(sB[4], sB[5]),  Y3 = pkbf16(sB[6], sB[7]);
        u32 Y4 = pkbf16(sB[8], sB[9]),  Y5 = pkbf16(sB[10], sB[11]);
        u32 Y6 = pkbf16(sB[12], sB[13]), Y7 = pkbf16(sB[14], sB[15]);
        auto b0 = __builtin_amdgcn_permlane32_swap(Y0, Y2, false, false);
        auto b1 = __builtin_amdgcn_permlane32_swap(Y1, Y3, false, false);
        auto b2 = __builtin_amdgcn_permlane32_swap(Y4, Y6, false, false);
        auto b3 = __builtin_amdgcn_permlane32_swap(Y5, Y7, false, false);
        const u32x4 wB1 = {(u32)b0[0], (u32)b1[0], (u32)b0[1], (u32)b1[1]};
        const u32x4 wB2 = {(u32)b2[0], (u32)b3[0], (u32)b2[1], (u32)b3[1]};
        const bf16x8 paB1 = __builtin_bit_cast(bf16x8, wB1);
        const bf16x8 paB2 = __builtin_bit_cast(bf16x8, wB2);
        lacB = __builtin_amdgcn_mfma_f32_32x32x16_bf16(paB1, ones, lacB, 0, 0, 0);
        lacB = __builtin_amdgcn_mfma_f32_32x32x16_bf16(paB2, ones, lacB, 0, 0, 0);
        // ---- group A (light) ----
        bf16x8 paA1, paA2;
        if (actA) {
          f32x16 sA = {};
          __builtin_amdgcn_s_setprio(1);
#pragma unroll
          for (int dg = 0; dg < 4; ++dg)
            sA = __builtin_amdgcn_mfma_f32_32x32x16_bf16(kf[dg], qfA[dg], sA,
                                                         0, 0, 0);
          __builtin_amdgcn_s_setprio(0);
          if (kb0 + 31 > qA0) {
            const int qabs = qA0 + c32;
            const int kbh = kb0 + 4 * h;
#pragma unroll
            for (int r = 0; r < 16; ++r)
              if (kbh + (r & 3) + 8 * (r >> 2) > qabs) sA[r] = -130.f;
          }
#pragma unroll
          for (int r = 0; r < 16; ++r) sA[r] = exp2f(sA[r]);
          u32 Z0 = pkbf16(sA[0], sA[1]),  Z1 = pkbf16(sA[2], sA[3]);
          u32 Z2 = pkbf16(sA[4], sA[5]),  Z3 = pkbf16(sA[6], sA[7]);
          u32 Z4 = pkbf16(sA[8], sA[9]),  Z5 = pkbf16(sA[10], sA[11]);
          u32 Z6 = pkbf16(sA[12], sA[13]), Z7 = pkbf16(sA[14], sA[15]);
          auto a0 = __builtin_amdgcn_permlane32_swap(Z0, Z2, false, false);
          auto a1 = __builtin_amdgcn_permlane32_swap(Z1, Z3, false, false);
          auto a2 = __builtin_amdgcn_permlane32_swap(Z4, Z6, false, false);
          auto a3 = __builtin_amdgcn_permlane32_swap(Z5, Z7, false, false);
          const u32x4 wA1 = {(u32)a0[0], (u32)a1[0], (u32)a0[1], (u32)a1[1]};
          const u32x4 wA2 = {(u32)a2[0], (u32)a3[0], (u32)a2[1], (u32)a3[1]};
          paA1 = __builtin_bit_cast(bf16x8, wA1);
          paA2 = __builtin_bit_cast(bf16x8, wA2);
          lacA = __builtin_amdgcn_mfma_f32_32x32x16_bf16(paA1, ones, lacA, 0, 0, 0);
          lacA = __builtin_amdgcn_mfma_f32_32x32x16_bf16(paA2, ones, lacA, 0, 0, 0);
        }
        // ---- PV for both groups (vf read once) ----
        __builtin_amdgcn_s_setprio(1);
#pragma unroll
        for (int dgb = 0; dgb < 2; ++dgb) {
          const int vrow = dgb * 32 + c32;
          const bf16x8 vf0 = *reinterpret_cast<const bf16x8*>(
              vl + vrow * 128 + (((ks * 4 + h) ^ (c32 & 7)) << 4));
          const bf16x8 vf1 = *reinterpret_cast<const bf16x8*>(
              vl + vrow * 128 + (((ks * 4 + 2 + h) ^ (c32 & 7)) << 4));
          if (dgb == 0) {
            o0B = __builtin_amdgcn_mfma_f32_32x32x16_bf16(paB1, vf0, o0B, 0, 0, 0);
            o0B = __builtin_amdgcn_mfma_f32_32x32x16_bf16(paB2, vf1, o0B, 0, 0, 0);
            if (actA) {
              o0A = __builtin_amdgcn_mfma_f32_32x32x16_bf16(paA1, vf0, o0A, 0, 0, 0);
              o0A = __builtin_amdgcn_mfma_f32_32x32x16_bf16(paA2, vf1, o0A, 0, 0, 0);
            }
          } else {
            o1B = __builtin_amdgcn_mfma_f32_32x32x16_bf16(paB1, vf0, o1B, 0, 0, 0);
            o1B = __builtin_amdgcn_mfma_f32_32x32x16_bf16(paB2, vf1, o1B, 0, 0, 0);
            if (actA) {
              o1A = __builtin_amdgcn_mfma_f32_32x32x16_bf16(paA1, vf0, o1A, 0, 0, 0);
              o1A = __builtin_amdgcn_mfma_f32_32x32x16_bf16(paA2, vf1, o1A, 0, 0, 0);
            }
          }
        }
        __builtin_amdgcn_s_setprio(0);
      }
    }
    __syncthreads();
  }

  // ---- epilogue: O[b][t][hh*64+d]; lac shares o's reg layout ----
  const int b = bh / H_, hh = bh - b * H_;
#pragma unroll
  for (int r = 0; r < 16; ++r) {
    const int qr = (r & 3) + 8 * (r >> 2) + 4 * h;
    const float lrA = 1.0f / lacA[r];
    const float lrB = 1.0f / lacB[r];
    const size_t rowA = ((size_t)(b * T_ + qA0 + qr)) * C_ + hh * HD_;
    const size_t rowB = ((size_t)(b * T_ + qB0 + qr)) * C_ + hh * HD_;
    O[rowA + c32] = (bf16_t)(o0A[r] * lrA);
    O[rowA + 32 + c32] = (bf16_t)(o1A[r] * lrA);
    O[rowB + c32] = (bf16_t)(o0B[r] * lrB);
    O[rowB + 32 + c32] = (bf16_t)(o1B[r] * lrB);
  }
}

// ---------------------------------------------------------------------------
extern "C" void kernel_launch(void* const* d_in, const int* in_sizes, int n_in,
                              void* d_out, int out_size, void* d_ws,
                              size_t ws_size, hipStream_t stream) {
  const float* x  = (const float*)d_in[0];   // [2,4096,768]
  const float* wa = (const float*)d_in[1];   // [2304,768]
  const float* wp = (const float*)d_in[2];   // [768,768]
  float* out = (float*)d_out;                // [2,4096,768] f32

  char* ws = (char*)d_ws;
  size_t off = 0;
  auto alloc = [&](size_t bytes) -> char* {
    char* p = ws + off;
    off += (bytes + 255) & ~(size_t)255;
    return p;
  };
  bf16_t* xb  = (bf16_t*)alloc((size_t)M_ * C_ * 2);
  bf16_t* wab = (bf16_t*)alloc((size_t)NQKV_ * C_ * 2);
  bf16_t* wpb = (bf16_t*)alloc((size_t)C_ * C_ * 2);
  bf16_t* Qb  = (bf16_t*)alloc((size_t)B_ * H_ * T_ * HD_ * 2);
  bf16_t* Kb  = (bf16_t*)alloc((size_t)B_ * H_ * T_ * HD_ * 2);
  bf16_t* Vtb = (bf16_t*)alloc((size_t)B_ * H_ * HD_ * T_ * 2);
  bf16_t* Ob  = (bf16_t*)alloc((size_t)M_ * C_ * 2);
  if (off > ws_size) return;

  cvt_f32_bf16_v4<<<512, 256, 0, stream>>>(x, xb, M_ * C_ / 4);
  cvt_f32_bf16_v4<<<512, 256, 0, stream>>>(wa, wab, NQKV_ * C_ / 4);
  cvt_f32_bf16_v4<<<256, 256, 0, stream>>>(wp, wpb, C_ * C_ / 4);

  gemm_qkv<<<dim3(NQKV_ / 128, M_ / 128), 256, 0, stream>>>(xb, wab, Qb, Kb, Vtb);
  attn_fwd<<<dim3(B_ * H_, 32), 128, 0, stream>>>(Qb, Kb, Vtb, Ob);
  gemm_proj<<<dim3(C_ / 128, M_ / 128), 256, 0, stream>>>(Ob, wpb, out);
}